// Round 10
// baseline (16.919 us; speedup 1.0000x reference)
//
#include <hip/hip_runtime.h>
#include <math.h>

// B=128, N=512, D=1024, C=512
// s: (128,1536) f32, a=s[:,:512], z=s[:,512:]; out: (128,1536) f32 = [da | dz]
// GEMM1: da = tanh([a|ctx](128x1024) @ [Wa;Wc](1024x512) + ba)
// GEMM2: c  = a(128x512) @ Wl(512x1024) + bl          -> ws
// dz[b,i] = sum_k c[b,k] * z[b,(i+k)%1024]
//
// k1 (exactly 256 blocks = 1/CU): GEMM2 job (32 rows x 16 cols, A coalesced
//     ->LDS frags, B gather, 2Mx4K waves, 4-way K reduce, c->ws) + inline
//     Apack: block bid packs fragment set (mt=bid>>5, ks=bid&31) on wave 0.
// k2 (512 blocks = 2/CU, parity-interleaved): even bid -> dz-v2 job
//     (packed f32x2 FMA, dual shifted LDS windows)  [R9-validated]
//     odd bid -> GEMM1 job (A from Apack, B gather LDS, 8-way K reduce, tanh)
//     [R8-validated]  -- pairing puts one VALU-heavy + one VMEM/MFMA-heavy
//     block per CU.
//
// ws: Apack @0 (256 KB) ; c @262144 (512 KB)
// Fragment k-slot bijection sigma(kq,j): j<4 -> 4kq+j ; j>=4 -> 16+4kq+(j-4),
// applied identically to A and B (validated rounds 2-9).

typedef float f32x4 __attribute__((ext_vector_type(4)));
typedef float f32x2 __attribute__((ext_vector_type(2)));
typedef float f32x4v __attribute__((ext_vector_type(4)));
typedef __bf16 bf16x8 __attribute__((ext_vector_type(8)));
typedef __bf16 bf16x4 __attribute__((ext_vector_type(4)));

#define C_OFF_BYTES 262144

__device__ __forceinline__ bf16x8 pack2(float4 v0, float4 v1) {
    bf16x8 r;
    r[0] = (__bf16)v0.x; r[1] = (__bf16)v0.y; r[2] = (__bf16)v0.z; r[3] = (__bf16)v0.w;
    r[4] = (__bf16)v1.x; r[5] = (__bf16)v1.y; r[6] = (__bf16)v1.z; r[7] = (__bf16)v1.w;
    return r;
}

__device__ __forceinline__ uint2 cvt4(float4 v) {
    bf16x4 r;
    r[0] = (__bf16)v.x; r[1] = (__bf16)v.y; r[2] = (__bf16)v.z; r[3] = (__bf16)v.w;
    return __builtin_bit_cast(uint2, r);
}

__device__ __forceinline__ f32x4 MFMA(uint4 a, uint4 b, f32x4 c) {
    return __builtin_amdgcn_mfma_f32_16x16x32_bf16(
        __builtin_bit_cast(bf16x8, a), __builtin_bit_cast(bf16x8, b), c, 0, 0, 0);
}

// ---------------------------------------------------------------------------
// k1: 256 blocks x 512 threads — GEMM2 + inline Apack
// ---------------------------------------------------------------------------
__global__ __launch_bounds__(512) void k1(
    const float* __restrict__ s, const float* __restrict__ ctx,
    const float* __restrict__ Wl, const float* __restrict__ bl,
    unsigned short* __restrict__ ws16, float* __restrict__ cws)
{
    __shared__ __align__(16) unsigned char smem[56832];

    const int bid = blockIdx.x;
    const int t = threadIdx.x;
    const int w = t >> 6, l = t & 63;
    const int lk = l & 15, kq = l >> 4;

    // ---- inline Apack: frag set (mtA=bid>>5, ksA=bid&31), idx = bid*64 + t
    if (t < 64) {
        const int ksA = bid & 31;
        const int lk2 = t & 15, kq2 = t >> 4;
        const int row = 16 * (bid >> 5) + lk2, kb = 32 * ksA;
        float4 v0, v1;
        if (ksA < 16) {
            v0 = *reinterpret_cast<const float4*>(s + (size_t)row * 1536 + kb + 4 * kq2);
            v1 = *reinterpret_cast<const float4*>(s + (size_t)row * 1536 + kb + 16 + 4 * kq2);
        } else {
            v0 = *reinterpret_cast<const float4*>(ctx + (size_t)row * 512 + (kb - 512) + 4 * kq2);
            v1 = *reinterpret_cast<const float4*>(ctx + (size_t)row * 512 + (kb - 512) + 16 + 4 * kq2);
        }
        bf16x8 fr = pack2(v0, v1);
        *reinterpret_cast<uint4*>(ws16 + ((size_t)bid * 64 + t) * 8) = __builtin_bit_cast(uint4, fr);
    }

    // ---------------- GEMM2: rows [32mt,32mt+32), cols [16nt,16nt+16)
    const int mt = bid >> 6, nt = bid & 63;
    const int col = nt * 16 + lk;
    unsigned short* Abuf = reinterpret_cast<unsigned short*>(smem);
    unsigned short* Bbuf = reinterpret_cast<unsigned short*>(smem + 32768);
    float* red = reinterpret_cast<float*>(smem + 49152);

    #pragma unroll 2
    for (int i = 0; i < 2; ++i) {
        const int ks = w * 2 + i;
        const int kb = ks * 32;
        bf16x8 fr;
        #pragma unroll
        for (int jj = 0; jj < 4; ++jj)
            fr[jj] = (__bf16)Wl[(size_t)(kb + 4 * kq + jj) * 1024 + col];
        #pragma unroll
        for (int jj = 0; jj < 4; ++jj)
            fr[4 + jj] = (__bf16)Wl[(size_t)(kb + 16 + 4 * kq + jj) * 1024 + col];
        *reinterpret_cast<uint4*>(&Bbuf[(ks * 64 + l) * 8]) = __builtin_bit_cast(uint4, fr);
    }

    {
        const int r = t >> 4;
        const int wmA = r >> 4, lkA = r & 15;
        const float* src = s + (size_t)(mt * 32 + r) * 1536;
        #pragma unroll 8
        for (int rep = 0; rep < 8; ++rep) {
            const int q = (t & 15) + 16 * rep;
            float4 v = *reinterpret_cast<const float4*>(src + 4 * q);
            const int ksA = q >> 3, kqA = q & 3, half = (q >> 2) & 1;
            const int off = ((wmA * 16 + ksA) * 64 + kqA * 16 + lkA) * 8 + half * 4;
            *reinterpret_cast<uint2*>(&Abuf[off]) = cvt4(v);
        }
    }
    __syncthreads();

    const int wm = w & 1, wk = w >> 1;
    f32x4 acc0 = (f32x4){0.f, 0.f, 0.f, 0.f};
    f32x4 acc1 = (f32x4){0.f, 0.f, 0.f, 0.f};
    #pragma unroll 4
    for (int i = 0; i < 4; ++i) {
        const int ks = wk * 4 + i;
        uint4 av = *reinterpret_cast<const uint4*>(&Abuf[((wm * 16 + ks) * 64 + l) * 8]);
        uint4 bv = *reinterpret_cast<const uint4*>(&Bbuf[(ks * 64 + l) * 8]);
        if (i & 1) acc1 = MFMA(av, bv, acc1);
        else       acc0 = MFMA(av, bv, acc0);
    }
    f32x4 sum = acc0 + acc1;

    if (wk > 0) {
        #pragma unroll
        for (int r = 0; r < 4; ++r)
            red[((wk - 1) * 32 + wm * 16 + 4 * kq + r) * 20 + lk] = sum[r];
    }
    __syncthreads();
    if (wk == 0) {
        const float bias = bl[col];
        #pragma unroll
        for (int r = 0; r < 4; ++r) {
            const int m = wm * 16 + 4 * kq + r;
            float v = sum[r] + red[m * 20 + lk] + red[(32 + m) * 20 + lk]
                    + red[(64 + m) * 20 + lk] + bias;
            cws[(size_t)(mt * 32 + m) * 1024 + col] = v;
        }
    }
}

// ---------------------------------------------------------------------------
// k2: 512 blocks x 512 threads — even bid: dz-v2 ; odd bid: GEMM1
// ---------------------------------------------------------------------------
__global__ __launch_bounds__(512) void k2(
    const float* __restrict__ s,
    const float* __restrict__ Wa, const float* __restrict__ Wc,
    const float* __restrict__ ba,
    const unsigned short* __restrict__ apack, const float* __restrict__ cws,
    float* __restrict__ out)
{
    __shared__ __align__(16) unsigned char smem[37888];

    const int bid = blockIdx.x;
    const int t = threadIdx.x;
    const int j = bid >> 1;

    if ((bid & 1) == 0) {
        // ---------------- dz-v2 (R9-validated): job j -> (b=j>>1, half=j&1)
        float* zdup = reinterpret_cast<float*>(smem);             // 2064 f @0
        float* zsh  = reinterpret_cast<float*>(smem + 8256);      // 2052 f
        float* part = reinterpret_cast<float*>(smem + 16464);     // 4096 f
        const int b = j >> 1;
        const int I0 = (j & 1) * 512;
        const float* zrow = s + (size_t)b * 1536 + 512;

        if (t < 256) {
            float4 v = reinterpret_cast<const float4*>(zrow)[t];
            reinterpret_cast<float4*>(zdup)[t] = v;
            reinterpret_cast<float4*>(zdup)[256 + t] = v;
        } else if (t == 256) {
            reinterpret_cast<float4*>(zdup)[512] = reinterpret_cast<const float4*>(zrow)[0];
        }
        __syncthreads();
        {
            f32x4v v0 = reinterpret_cast<const f32x4v*>(zdup)[t];
            f32x4v v1 = reinterpret_cast<const f32x4v*>(zdup)[t + 1];
            f32x4v r = {v0.y, v0.z, v0.w, v1.x};
            reinterpret_cast<f32x4v*>(zsh)[t] = r;
        }
        __syncthreads();

        const int g = t & 63;
        const int kq = __builtin_amdgcn_readfirstlane(t >> 6);
        const int i0 = 8 * g;
        const int koff = kq * 128;
        const int eb = (I0 + i0 + koff) >> 2;

        const f32x4v* zE = reinterpret_cast<const f32x4v*>(zdup);
        const f32x4v* zO = reinterpret_cast<const f32x4v*>(zsh);
        const f32x4v* c4 = reinterpret_cast<const f32x4v*>(cws + (size_t)b * 1024 + koff);

        f32x4v e0 = zE[eb], e1 = zE[eb + 1];
        f32x4v o0 = zO[eb], o1 = zO[eb + 1];
        f32x2 acc[8];
        #pragma unroll
        for (int q = 0; q < 8; ++q) acc[q] = (f32x2){0.f, 0.f};

        #pragma unroll 8
        for (int p2 = 0; p2 < 32; ++p2) {
            f32x4v cf = c4[p2];
            f32x4v e2 = zE[eb + p2 + 2];
            f32x4v o2 = zO[eb + p2 + 2];
            f32x2 cA = cf.lo, cB = cf.hi;
            acc[0] = __builtin_elementwise_fma(cA, e0.lo, acc[0]);
            acc[1] = __builtin_elementwise_fma(cA, o0.lo, acc[1]);
            acc[2] = __builtin_elementwise_fma(cA, e0.hi, acc[2]);
            acc[3] = __builtin_elementwise_fma(cA, o0.hi, acc[3]);
            acc[4] = __builtin_elementwise_fma(cA, e1.lo, acc[4]);
            acc[5] = __builtin_elementwise_fma(cA, o1.lo, acc[5]);
            acc[6] = __builtin_elementwise_fma(cA, e1.hi, acc[6]);
            acc[7] = __builtin_elementwise_fma(cA, o1.hi, acc[7]);
            acc[0] = __builtin_elementwise_fma(cB, e0.hi, acc[0]);
            acc[1] = __builtin_elementwise_fma(cB, o0.hi, acc[1]);
            acc[2] = __builtin_elementwise_fma(cB, e1.lo, acc[2]);
            acc[3] = __builtin_elementwise_fma(cB, o1.lo, acc[3]);
            acc[4] = __builtin_elementwise_fma(cB, e1.hi, acc[4]);
            acc[5] = __builtin_elementwise_fma(cB, o1.hi, acc[5]);
            acc[6] = __builtin_elementwise_fma(cB, e2.lo, acc[6]);
            acc[7] = __builtin_elementwise_fma(cB, o2.lo, acc[7]);
            e0 = e1; e1 = e2; o0 = o1; o1 = o2;
        }

        float4 r0, r1;
        r0.x = acc[0].x + acc[0].y; r0.y = acc[1].x + acc[1].y;
        r0.z = acc[2].x + acc[2].y; r0.w = acc[3].x + acc[3].y;
        r1.x = acc[4].x + acc[4].y; r1.y = acc[5].x + acc[5].y;
        r1.z = acc[6].x + acc[6].y; r1.w = acc[7].x + acc[7].y;
        reinterpret_cast<float4*>(&part[kq * 512 + i0])[0] = r0;
        reinterpret_cast<float4*>(&part[kq * 512 + i0])[1] = r1;
        __syncthreads();
        float sumz = 0.f;
        #pragma unroll
        for (int q = 0; q < 8; ++q) sumz += part[q * 512 + t];
        out[(size_t)b * 1536 + 512 + I0 + t] = sumz;
    } else {
        // ---------------- GEMM1 (R8-validated): job j -> (mt=j>>5, nt=j&31)
        unsigned short* Bg = reinterpret_cast<unsigned short*>(smem);   // 32KB
        float* red = reinterpret_cast<float*>(smem + 32768);
        const int mt = j >> 5, nt = j & 31;
        const int w = t >> 6, l = t & 63;
        const int lk = l & 15, kq = l >> 4;
        const int col = nt * 16 + lk;

        #pragma unroll 4
        for (int i = 0; i < 4; ++i) {
            const int ks = w * 4 + i;
            const int kb = ks * 32;
            const float* wb; int krel;
            if (ks < 16) { wb = Wa; krel = kb; } else { wb = Wc; krel = kb - 512; }
            bf16x8 fr;
            #pragma unroll
            for (int jj = 0; jj < 4; ++jj)
                fr[jj] = (__bf16)wb[(size_t)(krel + 4 * kq + jj) * 512 + col];
            #pragma unroll
            for (int jj = 0; jj < 4; ++jj)
                fr[4 + jj] = (__bf16)wb[(size_t)(krel + 16 + 4 * kq + jj) * 512 + col];
            *reinterpret_cast<uint4*>(&Bg[(ks * 64 + l) * 8]) = __builtin_bit_cast(uint4, fr);
        }
        __syncthreads();

        f32x4 acc0 = (f32x4){0.f, 0.f, 0.f, 0.f};
        f32x4 acc1 = (f32x4){0.f, 0.f, 0.f, 0.f};
        #pragma unroll 4
        for (int i = 0; i < 4; ++i) {
            const int ks = w * 4 + i;
            uint4 av = *reinterpret_cast<const uint4*>(apack + ((size_t)(mt * 32 + ks) * 64 + l) * 8);
            uint4 bv = *reinterpret_cast<const uint4*>(&Bg[(ks * 64 + l) * 8]);
            if (i & 1) acc1 = MFMA(av, bv, acc1);
            else       acc0 = MFMA(av, bv, acc0);
        }
        f32x4 sum = acc0 + acc1;

        if (w < 4) {
            #pragma unroll
            for (int r = 0; r < 4; ++r)
                red[w * 272 + (kq * 4 + r) * 17 + lk] = sum[r];
        }
        __syncthreads();
        if (w >= 4) {
            #pragma unroll
            for (int r = 0; r < 4; ++r)
                red[(w - 4) * 272 + (kq * 4 + r) * 17 + lk] += sum[r];
        }
        __syncthreads();
        if (t < 256) {
            const int m = t >> 4, n = t & 15;
            const int o = m * 17 + n;
            const int colo = nt * 16 + n;
            float v = red[o] + red[272 + o] + red[544 + o] + red[816 + o] + ba[colo];
            out[(size_t)(mt * 16 + m) * 1536 + colo] = tanhf(v);
        }
    }
}

extern "C" void kernel_launch(void* const* d_in, const int* in_sizes, int n_in,
                              void* d_out, int out_size, void* d_ws, size_t ws_size,
                              hipStream_t stream) {
    // inputs: 0=t, 1=s, 2=context, 3=Wa, 4=Wc, 5=ba, 6=Wl, 7=bl
    const float* s   = (const float*)d_in[1];
    const float* ctx = (const float*)d_in[2];
    const float* Wa  = (const float*)d_in[3];
    const float* Wc  = (const float*)d_in[4];
    const float* ba  = (const float*)d_in[5];
    const float* Wl  = (const float*)d_in[6];
    const float* bl  = (const float*)d_in[7];
    float* out = (float*)d_out;

    unsigned short* ws16 = (unsigned short*)d_ws;
    float* cws = (float*)((char*)d_ws + C_OFF_BYTES);

    k1<<<256, 512, 0, stream>>>(s, ctx, Wl, bl, ws16, cws);
    k2<<<512, 512, 0, stream>>>(s, Wa, Wc, ba, ws16, cws, out);
}

// Round 11
// 15.262 us; speedup vs baseline: 1.1086x; 1.1086x over previous
//
#include <hip/hip_runtime.h>
#include <math.h>

// B=128, N=512, D=1024, C=512
// s: (128,1536) f32, a=s[:,:512], z=s[:,512:]; out: (128,1536) f32 = [da | dz]
// GEMM1: da = tanh([a|ctx](128x1024) @ [Wa;Wc](1024x512) + ba)
// GEMM2: c  = a(128x512) @ Wl(512x1024) + bl          -> ws
// dz[b,i] = sum_k c[b,k] * z[b,(i+k)%1024]
//
// k1 (exactly 256 blocks = 1/CU): GEMM2 job (32 rows x 16 cols, A coalesced
//     ->LDS frags, B gather, 2Mx4K waves, 4-way K reduce, c->ws) + inline
//     Apack on wave 0 (block bid packs fragment set (mt=bid>>5, ks=bid&31)).
//     [R10-validated]
// k2 (512 blocks): [0,256) dz-v2 (packed f32x2 FMA, dual shifted windows);
//     [256,512) GEMM1 (A from Apack, B gather LDS, 8-way K reduce, tanh).
//     RANGE split (NOT parity): CU c receives blocks c and c+256 -> exactly
//     one dz + one GEMM1 per CU (R10's parity interleave gave two-of-same
//     per CU and regressed; R9 range split is the validated optimum).
//
// ws: Apack @0 (256 KB) ; c @262144 (512 KB)
// Fragment k-slot bijection sigma(kq,j): j<4 -> 4kq+j ; j>=4 -> 16+4kq+(j-4),
// applied identically to A and B (validated rounds 2-10).

typedef float f32x4 __attribute__((ext_vector_type(4)));
typedef float f32x2 __attribute__((ext_vector_type(2)));
typedef float f32x4v __attribute__((ext_vector_type(4)));
typedef __bf16 bf16x8 __attribute__((ext_vector_type(8)));
typedef __bf16 bf16x4 __attribute__((ext_vector_type(4)));

#define C_OFF_BYTES 262144

__device__ __forceinline__ bf16x8 pack2(float4 v0, float4 v1) {
    bf16x8 r;
    r[0] = (__bf16)v0.x; r[1] = (__bf16)v0.y; r[2] = (__bf16)v0.z; r[3] = (__bf16)v0.w;
    r[4] = (__bf16)v1.x; r[5] = (__bf16)v1.y; r[6] = (__bf16)v1.z; r[7] = (__bf16)v1.w;
    return r;
}

__device__ __forceinline__ uint2 cvt4(float4 v) {
    bf16x4 r;
    r[0] = (__bf16)v.x; r[1] = (__bf16)v.y; r[2] = (__bf16)v.z; r[3] = (__bf16)v.w;
    return __builtin_bit_cast(uint2, r);
}

__device__ __forceinline__ f32x4 MFMA(uint4 a, uint4 b, f32x4 c) {
    return __builtin_amdgcn_mfma_f32_16x16x32_bf16(
        __builtin_bit_cast(bf16x8, a), __builtin_bit_cast(bf16x8, b), c, 0, 0, 0);
}

// ---------------------------------------------------------------------------
// k1: 256 blocks x 512 threads — GEMM2 + inline Apack  [R10-validated]
// ---------------------------------------------------------------------------
__global__ __launch_bounds__(512) void k1(
    const float* __restrict__ s, const float* __restrict__ ctx,
    const float* __restrict__ Wl, const float* __restrict__ bl,
    unsigned short* __restrict__ ws16, float* __restrict__ cws)
{
    __shared__ __align__(16) unsigned char smem[56832];

    const int bid = blockIdx.x;
    const int t = threadIdx.x;
    const int w = t >> 6, l = t & 63;
    const int lk = l & 15, kq = l >> 4;

    // ---- inline Apack: frag set (mtA=bid>>5, ksA=bid&31), idx = bid*64 + t
    if (t < 64) {
        const int ksA = bid & 31;
        const int lk2 = t & 15, kq2 = t >> 4;
        const int row = 16 * (bid >> 5) + lk2, kb = 32 * ksA;
        float4 v0, v1;
        if (ksA < 16) {
            v0 = *reinterpret_cast<const float4*>(s + (size_t)row * 1536 + kb + 4 * kq2);
            v1 = *reinterpret_cast<const float4*>(s + (size_t)row * 1536 + kb + 16 + 4 * kq2);
        } else {
            v0 = *reinterpret_cast<const float4*>(ctx + (size_t)row * 512 + (kb - 512) + 4 * kq2);
            v1 = *reinterpret_cast<const float4*>(ctx + (size_t)row * 512 + (kb - 512) + 16 + 4 * kq2);
        }
        bf16x8 fr = pack2(v0, v1);
        *reinterpret_cast<uint4*>(ws16 + ((size_t)bid * 64 + t) * 8) = __builtin_bit_cast(uint4, fr);
    }

    // ---------------- GEMM2: rows [32mt,32mt+32), cols [16nt,16nt+16)
    const int mt = bid >> 6, nt = bid & 63;
    const int col = nt * 16 + lk;
    unsigned short* Abuf = reinterpret_cast<unsigned short*>(smem);
    unsigned short* Bbuf = reinterpret_cast<unsigned short*>(smem + 32768);
    float* red = reinterpret_cast<float*>(smem + 49152);

    #pragma unroll 2
    for (int i = 0; i < 2; ++i) {
        const int ks = w * 2 + i;
        const int kb = ks * 32;
        bf16x8 fr;
        #pragma unroll
        for (int jj = 0; jj < 4; ++jj)
            fr[jj] = (__bf16)Wl[(size_t)(kb + 4 * kq + jj) * 1024 + col];
        #pragma unroll
        for (int jj = 0; jj < 4; ++jj)
            fr[4 + jj] = (__bf16)Wl[(size_t)(kb + 16 + 4 * kq + jj) * 1024 + col];
        *reinterpret_cast<uint4*>(&Bbuf[(ks * 64 + l) * 8]) = __builtin_bit_cast(uint4, fr);
    }

    {
        const int r = t >> 4;
        const int wmA = r >> 4, lkA = r & 15;
        const float* src = s + (size_t)(mt * 32 + r) * 1536;
        #pragma unroll 8
        for (int rep = 0; rep < 8; ++rep) {
            const int q = (t & 15) + 16 * rep;
            float4 v = *reinterpret_cast<const float4*>(src + 4 * q);
            const int ksA = q >> 3, kqA = q & 3, half = (q >> 2) & 1;
            const int off = ((wmA * 16 + ksA) * 64 + kqA * 16 + lkA) * 8 + half * 4;
            *reinterpret_cast<uint2*>(&Abuf[off]) = cvt4(v);
        }
    }
    __syncthreads();

    const int wm = w & 1, wk = w >> 1;
    f32x4 acc0 = (f32x4){0.f, 0.f, 0.f, 0.f};
    f32x4 acc1 = (f32x4){0.f, 0.f, 0.f, 0.f};
    #pragma unroll 4
    for (int i = 0; i < 4; ++i) {
        const int ks = wk * 4 + i;
        uint4 av = *reinterpret_cast<const uint4*>(&Abuf[((wm * 16 + ks) * 64 + l) * 8]);
        uint4 bv = *reinterpret_cast<const uint4*>(&Bbuf[(ks * 64 + l) * 8]);
        if (i & 1) acc1 = MFMA(av, bv, acc1);
        else       acc0 = MFMA(av, bv, acc0);
    }
    f32x4 sum = acc0 + acc1;

    if (wk > 0) {
        #pragma unroll
        for (int r = 0; r < 4; ++r)
            red[((wk - 1) * 32 + wm * 16 + 4 * kq + r) * 20 + lk] = sum[r];
    }
    __syncthreads();
    if (wk == 0) {
        const float bias = bl[col];
        #pragma unroll
        for (int r = 0; r < 4; ++r) {
            const int m = wm * 16 + 4 * kq + r;
            float v = sum[r] + red[m * 20 + lk] + red[(32 + m) * 20 + lk]
                    + red[(64 + m) * 20 + lk] + bias;
            cws[(size_t)(mt * 32 + m) * 1024 + col] = v;
        }
    }
}

// ---------------------------------------------------------------------------
// k2: 512 blocks x 512 threads.  [0,256): dz-v2 ; [256,512): GEMM1
// (R9-validated mapping: CU c gets block c (dz) + block c+256 (GEMM1))
// ---------------------------------------------------------------------------
__global__ __launch_bounds__(512) void k2(
    const float* __restrict__ s,
    const float* __restrict__ Wa, const float* __restrict__ Wc,
    const float* __restrict__ ba,
    const unsigned short* __restrict__ apack, const float* __restrict__ cws,
    float* __restrict__ out)
{
    __shared__ __align__(16) unsigned char smem[37888];

    const int bid = blockIdx.x;
    const int t = threadIdx.x;

    if (bid < 256) {
        // ---------------- dz-v2 (R9-validated): job bid -> (b=bid>>1, half)
        float* zdup = reinterpret_cast<float*>(smem);             // 2064 f @0
        float* zsh  = reinterpret_cast<float*>(smem + 8256);      // 2052 f
        float* part = reinterpret_cast<float*>(smem + 16464);     // 4096 f
        const int b = bid >> 1;
        const int I0 = (bid & 1) * 512;
        const float* zrow = s + (size_t)b * 1536 + 512;

        if (t < 256) {
            float4 v = reinterpret_cast<const float4*>(zrow)[t];
            reinterpret_cast<float4*>(zdup)[t] = v;
            reinterpret_cast<float4*>(zdup)[256 + t] = v;
        } else if (t == 256) {
            reinterpret_cast<float4*>(zdup)[512] = reinterpret_cast<const float4*>(zrow)[0];
        }
        __syncthreads();
        {
            f32x4v v0 = reinterpret_cast<const f32x4v*>(zdup)[t];
            f32x4v v1 = reinterpret_cast<const f32x4v*>(zdup)[t + 1];
            f32x4v r = {v0.y, v0.z, v0.w, v1.x};
            reinterpret_cast<f32x4v*>(zsh)[t] = r;
        }
        __syncthreads();

        const int g = t & 63;
        const int kq = __builtin_amdgcn_readfirstlane(t >> 6);
        const int i0 = 8 * g;
        const int koff = kq * 128;
        const int eb = (I0 + i0 + koff) >> 2;

        const f32x4v* zE = reinterpret_cast<const f32x4v*>(zdup);
        const f32x4v* zO = reinterpret_cast<const f32x4v*>(zsh);
        const f32x4v* c4 = reinterpret_cast<const f32x4v*>(cws + (size_t)b * 1024 + koff);

        f32x4v e0 = zE[eb], e1 = zE[eb + 1];
        f32x4v o0 = zO[eb], o1 = zO[eb + 1];
        f32x2 acc[8];
        #pragma unroll
        for (int q = 0; q < 8; ++q) acc[q] = (f32x2){0.f, 0.f};

        #pragma unroll 8
        for (int p2 = 0; p2 < 32; ++p2) {
            f32x4v cf = c4[p2];
            f32x4v e2 = zE[eb + p2 + 2];
            f32x4v o2 = zO[eb + p2 + 2];
            f32x2 cA = cf.lo, cB = cf.hi;
            acc[0] = __builtin_elementwise_fma(cA, e0.lo, acc[0]);
            acc[1] = __builtin_elementwise_fma(cA, o0.lo, acc[1]);
            acc[2] = __builtin_elementwise_fma(cA, e0.hi, acc[2]);
            acc[3] = __builtin_elementwise_fma(cA, o0.hi, acc[3]);
            acc[4] = __builtin_elementwise_fma(cA, e1.lo, acc[4]);
            acc[5] = __builtin_elementwise_fma(cA, o1.lo, acc[5]);
            acc[6] = __builtin_elementwise_fma(cA, e1.hi, acc[6]);
            acc[7] = __builtin_elementwise_fma(cA, o1.hi, acc[7]);
            acc[0] = __builtin_elementwise_fma(cB, e0.hi, acc[0]);
            acc[1] = __builtin_elementwise_fma(cB, o0.hi, acc[1]);
            acc[2] = __builtin_elementwise_fma(cB, e1.lo, acc[2]);
            acc[3] = __builtin_elementwise_fma(cB, o1.lo, acc[3]);
            acc[4] = __builtin_elementwise_fma(cB, e1.hi, acc[4]);
            acc[5] = __builtin_elementwise_fma(cB, o1.hi, acc[5]);
            acc[6] = __builtin_elementwise_fma(cB, e2.lo, acc[6]);
            acc[7] = __builtin_elementwise_fma(cB, o2.lo, acc[7]);
            e0 = e1; e1 = e2; o0 = o1; o1 = o2;
        }

        float4 r0, r1;
        r0.x = acc[0].x + acc[0].y; r0.y = acc[1].x + acc[1].y;
        r0.z = acc[2].x + acc[2].y; r0.w = acc[3].x + acc[3].y;
        r1.x = acc[4].x + acc[4].y; r1.y = acc[5].x + acc[5].y;
        r1.z = acc[6].x + acc[6].y; r1.w = acc[7].x + acc[7].y;
        reinterpret_cast<float4*>(&part[kq * 512 + i0])[0] = r0;
        reinterpret_cast<float4*>(&part[kq * 512 + i0])[1] = r1;
        __syncthreads();
        float sumz = 0.f;
        #pragma unroll
        for (int q = 0; q < 8; ++q) sumz += part[q * 512 + t];
        out[(size_t)b * 1536 + 512 + I0 + t] = sumz;
    } else {
        // ---------------- GEMM1 (R8-validated): job j -> (mt=j>>5, nt=j&31)
        unsigned short* Bg = reinterpret_cast<unsigned short*>(smem);   // 32KB
        float* red = reinterpret_cast<float*>(smem + 32768);
        const int j = bid - 256;
        const int mt = j >> 5, nt = j & 31;
        const int w = t >> 6, l = t & 63;
        const int lk = l & 15, kq = l >> 4;
        const int col = nt * 16 + lk;

        #pragma unroll 4
        for (int i = 0; i < 4; ++i) {
            const int ks = w * 4 + i;
            const int kb = ks * 32;
            const float* wb; int krel;
            if (ks < 16) { wb = Wa; krel = kb; } else { wb = Wc; krel = kb - 512; }
            bf16x8 fr;
            #pragma unroll
            for (int jj = 0; jj < 4; ++jj)
                fr[jj] = (__bf16)wb[(size_t)(krel + 4 * kq + jj) * 512 + col];
            #pragma unroll
            for (int jj = 0; jj < 4; ++jj)
                fr[4 + jj] = (__bf16)wb[(size_t)(krel + 16 + 4 * kq + jj) * 512 + col];
            *reinterpret_cast<uint4*>(&Bg[(ks * 64 + l) * 8]) = __builtin_bit_cast(uint4, fr);
        }
        __syncthreads();

        f32x4 acc0 = (f32x4){0.f, 0.f, 0.f, 0.f};
        f32x4 acc1 = (f32x4){0.f, 0.f, 0.f, 0.f};
        #pragma unroll 4
        for (int i = 0; i < 4; ++i) {
            const int ks = w * 4 + i;
            uint4 av = *reinterpret_cast<const uint4*>(apack + ((size_t)(mt * 32 + ks) * 64 + l) * 8);
            uint4 bv = *reinterpret_cast<const uint4*>(&Bg[(ks * 64 + l) * 8]);
            if (i & 1) acc1 = MFMA(av, bv, acc1);
            else       acc0 = MFMA(av, bv, acc0);
        }
        f32x4 sum = acc0 + acc1;

        if (w < 4) {
            #pragma unroll
            for (int r = 0; r < 4; ++r)
                red[w * 272 + (kq * 4 + r) * 17 + lk] = sum[r];
        }
        __syncthreads();
        if (w >= 4) {
            #pragma unroll
            for (int r = 0; r < 4; ++r)
                red[(w - 4) * 272 + (kq * 4 + r) * 17 + lk] += sum[r];
        }
        __syncthreads();
        if (t < 256) {
            const int m = t >> 4, n = t & 15;
            const int o = m * 17 + n;
            const int colo = nt * 16 + n;
            float v = red[o] + red[272 + o] + red[544 + o] + red[816 + o] + ba[colo];
            out[(size_t)(mt * 16 + m) * 1536 + colo] = tanhf(v);
        }
    }
}

extern "C" void kernel_launch(void* const* d_in, const int* in_sizes, int n_in,
                              void* d_out, int out_size, void* d_ws, size_t ws_size,
                              hipStream_t stream) {
    // inputs: 0=t, 1=s, 2=context, 3=Wa, 4=Wc, 5=ba, 6=Wl, 7=bl
    const float* s   = (const float*)d_in[1];
    const float* ctx = (const float*)d_in[2];
    const float* Wa  = (const float*)d_in[3];
    const float* Wc  = (const float*)d_in[4];
    const float* ba  = (const float*)d_in[5];
    const float* Wl  = (const float*)d_in[6];
    const float* bl  = (const float*)d_in[7];
    float* out = (float*)d_out;

    unsigned short* ws16 = (unsigned short*)d_ws;
    float* cws = (float*)((char*)d_ws + C_OFF_BYTES);

    k1<<<256, 512, 0, stream>>>(s, ctx, Wl, bl, ws16, cws);
    k2<<<512, 512, 0, stream>>>(s, Wa, Wc, ba, ws16, cws, out);
}

// Round 12
// 14.547 us; speedup vs baseline: 1.1631x; 1.0492x over previous
//
#include <hip/hip_runtime.h>
#include <math.h>

// B=128, N=512, D=1024, C=512
// s: (128,1536) f32, a=s[:,:512], z=s[:,512:]; out: (128,1536) f32 = [da | dz]
// GEMM1: da = tanh([a|ctx](128x1024) @ [Wa;Wc](1024x512) + ba)
// GEMM2: c  = a(128x512) @ Wl(512x1024) + bl          -> ws
// dz[b,i] = sum_k c[b,k] * z[b,(i+k)%1024]
//
// Structure = R9 (best measured: 14.6us), with ONE change: k1's GEMM2
// B-staging uses coalesced float4 loads + LDS scatter instead of 16 scalar
// k-gather loads per thread.
//   k1 (272 blocks): [0,256) GEMM2 (A coalesced->LDS frags, B float4+scatter,
//       2Mx4K waves, 4-way K reduce, c->ws); [256,272) Apack.
//   k2 (512 blocks): [0,256) dz-v2 (packed f32x2 FMA, dual shifted windows);
//       [256,512) GEMM1 (A from Apack, B gather LDS, 8-way K reduce, tanh).
//       Range split: CU c gets one dz + one GEMM1 (validated optimum).
//
// ws: Apack @0 (256 KB) ; c @262144 (512 KB)
// Fragment k-slot bijection sigma(kq,j): j<4 -> 4kq+j ; j>=4 -> 16+4kq+(j-4),
// applied identically to A and B (validated rounds 2-11).
// Scatter form: for element (k,col): ks=k>>5, kr=k&31, lane=16*((kr&15)>>2)
// + (col-N0), j=(kr&3)+4*(kr>>4), u16 offset=(ks*64+lane)*8+j.

typedef float f32x4 __attribute__((ext_vector_type(4)));
typedef float f32x2 __attribute__((ext_vector_type(2)));
typedef float f32x4v __attribute__((ext_vector_type(4)));
typedef __bf16 bf16x8 __attribute__((ext_vector_type(8)));
typedef __bf16 bf16x4 __attribute__((ext_vector_type(4)));

#define C_OFF_BYTES 262144

__device__ __forceinline__ bf16x8 pack2(float4 v0, float4 v1) {
    bf16x8 r;
    r[0] = (__bf16)v0.x; r[1] = (__bf16)v0.y; r[2] = (__bf16)v0.z; r[3] = (__bf16)v0.w;
    r[4] = (__bf16)v1.x; r[5] = (__bf16)v1.y; r[6] = (__bf16)v1.z; r[7] = (__bf16)v1.w;
    return r;
}

__device__ __forceinline__ uint2 cvt4(float4 v) {
    bf16x4 r;
    r[0] = (__bf16)v.x; r[1] = (__bf16)v.y; r[2] = (__bf16)v.z; r[3] = (__bf16)v.w;
    return __builtin_bit_cast(uint2, r);
}

__device__ __forceinline__ unsigned short bf16u(float f) {
    return __builtin_bit_cast(unsigned short, (__bf16)f);
}

__device__ __forceinline__ f32x4 MFMA(uint4 a, uint4 b, f32x4 c) {
    return __builtin_amdgcn_mfma_f32_16x16x32_bf16(
        __builtin_bit_cast(bf16x8, a), __builtin_bit_cast(bf16x8, b), c, 0, 0, 0);
}

// ---------------------------------------------------------------------------
// k1: 272 blocks x 512 threads.  [0,256): GEMM2 ; [256,272): Apack
// ---------------------------------------------------------------------------
__global__ __launch_bounds__(512) void k1(
    const float* __restrict__ s, const float* __restrict__ ctx,
    const float* __restrict__ Wl, const float* __restrict__ bl,
    unsigned short* __restrict__ ws16, float* __restrict__ cws)
{
    __shared__ __align__(16) unsigned char smem[56832];

    const int bid = blockIdx.x;
    const int t = threadIdx.x;
    const int w = t >> 6, l = t & 63;
    const int lk = l & 15, kq = l >> 4;

    if (bid < 256) {
        // ---------------- GEMM2: rows [32mt,32mt+32), cols [16nt,16nt+16)
        const int mt = bid >> 6, nt = bid & 63;
        const int col = nt * 16 + lk;
        const int N0 = nt * 16;
        unsigned short* Abuf = reinterpret_cast<unsigned short*>(smem);
        unsigned short* Bbuf = reinterpret_cast<unsigned short*>(smem + 32768);
        float* red = reinterpret_cast<float*>(smem + 49152);

        // ---- stage B: coalesced float4 loads + LDS scatter (NEW this round)
        {
            const int q = t & 3;                 // col quad: cols N0+4q..N0+4q+3
            const int r0 = t >> 2;               // 0..127
            #pragma unroll 4
            for (int p = 0; p < 4; ++p) {
                const int k = r0 + 128 * p;      // 0..511
                float4 v = *reinterpret_cast<const float4*>(
                    Wl + (size_t)k * 1024 + N0 + 4 * q);
                const int ks = k >> 5, kr = k & 31;
                const int kqs = (kr & 15) >> 2;
                const int jj = (kr & 3) + 4 * (kr >> 4);
                const int base = (ks * 64 + 16 * kqs + 4 * q) * 8 + jj;
                Bbuf[base]      = bf16u(v.x);
                Bbuf[base + 8]  = bf16u(v.y);
                Bbuf[base + 16] = bf16u(v.z);
                Bbuf[base + 24] = bf16u(v.w);
            }
        }

        // ---- stage A coalesced -> fragment-layout LDS (R8-validated)
        {
            const int r = t >> 4;
            const int wmA = r >> 4, lkA = r & 15;
            const float* src = s + (size_t)(mt * 32 + r) * 1536;
            #pragma unroll 8
            for (int rep = 0; rep < 8; ++rep) {
                const int q = (t & 15) + 16 * rep;
                float4 v = *reinterpret_cast<const float4*>(src + 4 * q);
                const int ksA = q >> 3, kqA = q & 3, half = (q >> 2) & 1;
                const int off = ((wmA * 16 + ksA) * 64 + kqA * 16 + lkA) * 8 + half * 4;
                *reinterpret_cast<uint2*>(&Abuf[off]) = cvt4(v);
            }
        }
        __syncthreads();

        const int wm = w & 1, wk = w >> 1;
        f32x4 acc0 = (f32x4){0.f, 0.f, 0.f, 0.f};
        f32x4 acc1 = (f32x4){0.f, 0.f, 0.f, 0.f};
        #pragma unroll 4
        for (int i = 0; i < 4; ++i) {
            const int ks = wk * 4 + i;
            uint4 av = *reinterpret_cast<const uint4*>(&Abuf[((wm * 16 + ks) * 64 + l) * 8]);
            uint4 bv = *reinterpret_cast<const uint4*>(&Bbuf[(ks * 64 + l) * 8]);
            if (i & 1) acc1 = MFMA(av, bv, acc1);
            else       acc0 = MFMA(av, bv, acc0);
        }
        f32x4 sum = acc0 + acc1;

        if (wk > 0) {
            #pragma unroll
            for (int r = 0; r < 4; ++r)
                red[((wk - 1) * 32 + wm * 16 + 4 * kq + r) * 20 + lk] = sum[r];
        }
        __syncthreads();
        if (wk == 0) {
            const float bias = bl[col];
            #pragma unroll
            for (int r = 0; r < 4; ++r) {
                const int m = wm * 16 + 4 * kq + r;
                float v = sum[r] + red[m * 20 + lk] + red[(32 + m) * 20 + lk]
                        + red[(64 + m) * 20 + lk] + bias;
                cws[(size_t)(mt * 32 + m) * 1024 + col] = v;
            }
        }
    } else {
        // ---------------- Apack (R9-validated)
        const int base = (bid - 256) * 512 + t;
        #pragma unroll 2
        for (int rep = 0; rep < 2; ++rep) {
            const int idx = base + rep * 8192;
            const int mt = idx >> 11, ks = (idx >> 6) & 31, l2 = idx & 63;
            const int lk2 = l2 & 15, kq2 = l2 >> 4;
            const int row = 16 * mt + lk2, kb = 32 * ks;
            float4 v0, v1;
            if (ks < 16) {
                v0 = *reinterpret_cast<const float4*>(s + (size_t)row * 1536 + kb + 4 * kq2);
                v1 = *reinterpret_cast<const float4*>(s + (size_t)row * 1536 + kb + 16 + 4 * kq2);
            } else {
                v0 = *reinterpret_cast<const float4*>(ctx + (size_t)row * 512 + (kb - 512) + 4 * kq2);
                v1 = *reinterpret_cast<const float4*>(ctx + (size_t)row * 512 + (kb - 512) + 16 + 4 * kq2);
            }
            bf16x8 fr = pack2(v0, v1);
            *reinterpret_cast<uint4*>(ws16 + (size_t)idx * 8) = __builtin_bit_cast(uint4, fr);
        }
    }
}

// ---------------------------------------------------------------------------
// k2: 512 blocks x 512 threads.  [0,256): dz-v2 ; [256,512): GEMM1
// (R9-validated verbatim)
// ---------------------------------------------------------------------------
__global__ __launch_bounds__(512) void k2(
    const float* __restrict__ s,
    const float* __restrict__ Wa, const float* __restrict__ Wc,
    const float* __restrict__ ba,
    const unsigned short* __restrict__ apack, const float* __restrict__ cws,
    float* __restrict__ out)
{
    __shared__ __align__(16) unsigned char smem[37888];

    const int bid = blockIdx.x;
    const int t = threadIdx.x;

    if (bid < 256) {
        // ---------------- dz-v2: packed f32x2 FMA, dual shifted windows
        float* zdup = reinterpret_cast<float*>(smem);             // 2064 f @0
        float* zsh  = reinterpret_cast<float*>(smem + 8256);      // 2052 f
        float* part = reinterpret_cast<float*>(smem + 16464);     // 4096 f
        const int b = bid >> 1;
        const int I0 = (bid & 1) * 512;
        const float* zrow = s + (size_t)b * 1536 + 512;

        if (t < 256) {
            float4 v = reinterpret_cast<const float4*>(zrow)[t];
            reinterpret_cast<float4*>(zdup)[t] = v;
            reinterpret_cast<float4*>(zdup)[256 + t] = v;
        } else if (t == 256) {
            reinterpret_cast<float4*>(zdup)[512] = reinterpret_cast<const float4*>(zrow)[0];
        }
        __syncthreads();
        {
            f32x4v v0 = reinterpret_cast<const f32x4v*>(zdup)[t];
            f32x4v v1 = reinterpret_cast<const f32x4v*>(zdup)[t + 1];
            f32x4v r = {v0.y, v0.z, v0.w, v1.x};
            reinterpret_cast<f32x4v*>(zsh)[t] = r;
        }
        __syncthreads();

        const int g = t & 63;
        const int kq = __builtin_amdgcn_readfirstlane(t >> 6);
        const int i0 = 8 * g;
        const int koff = kq * 128;
        const int eb = (I0 + i0 + koff) >> 2;

        const f32x4v* zE = reinterpret_cast<const f32x4v*>(zdup);
        const f32x4v* zO = reinterpret_cast<const f32x4v*>(zsh);
        const f32x4v* c4 = reinterpret_cast<const f32x4v*>(cws + (size_t)b * 1024 + koff);

        f32x4v e0 = zE[eb], e1 = zE[eb + 1];
        f32x4v o0 = zO[eb], o1 = zO[eb + 1];
        f32x2 acc[8];
        #pragma unroll
        for (int q = 0; q < 8; ++q) acc[q] = (f32x2){0.f, 0.f};

        #pragma unroll 8
        for (int p2 = 0; p2 < 32; ++p2) {
            f32x4v cf = c4[p2];
            f32x4v e2 = zE[eb + p2 + 2];
            f32x4v o2 = zO[eb + p2 + 2];
            f32x2 cA = cf.lo, cB = cf.hi;
            acc[0] = __builtin_elementwise_fma(cA, e0.lo, acc[0]);
            acc[1] = __builtin_elementwise_fma(cA, o0.lo, acc[1]);
            acc[2] = __builtin_elementwise_fma(cA, e0.hi, acc[2]);
            acc[3] = __builtin_elementwise_fma(cA, o0.hi, acc[3]);
            acc[4] = __builtin_elementwise_fma(cA, e1.lo, acc[4]);
            acc[5] = __builtin_elementwise_fma(cA, o1.lo, acc[5]);
            acc[6] = __builtin_elementwise_fma(cA, e1.hi, acc[6]);
            acc[7] = __builtin_elementwise_fma(cA, o1.hi, acc[7]);
            acc[0] = __builtin_elementwise_fma(cB, e0.hi, acc[0]);
            acc[1] = __builtin_elementwise_fma(cB, o0.hi, acc[1]);
            acc[2] = __builtin_elementwise_fma(cB, e1.lo, acc[2]);
            acc[3] = __builtin_elementwise_fma(cB, o1.lo, acc[3]);
            acc[4] = __builtin_elementwise_fma(cB, e1.hi, acc[4]);
            acc[5] = __builtin_elementwise_fma(cB, o1.hi, acc[5]);
            acc[6] = __builtin_elementwise_fma(cB, e2.lo, acc[6]);
            acc[7] = __builtin_elementwise_fma(cB, o2.lo, acc[7]);
            e0 = e1; e1 = e2; o0 = o1; o1 = o2;
        }

        float4 r0, r1;
        r0.x = acc[0].x + acc[0].y; r0.y = acc[1].x + acc[1].y;
        r0.z = acc[2].x + acc[2].y; r0.w = acc[3].x + acc[3].y;
        r1.x = acc[4].x + acc[4].y; r1.y = acc[5].x + acc[5].y;
        r1.z = acc[6].x + acc[6].y; r1.w = acc[7].x + acc[7].y;
        reinterpret_cast<float4*>(&part[kq * 512 + i0])[0] = r0;
        reinterpret_cast<float4*>(&part[kq * 512 + i0])[1] = r1;
        __syncthreads();
        float sumz = 0.f;
        #pragma unroll
        for (int q = 0; q < 8; ++q) sumz += part[q * 512 + t];
        out[(size_t)b * 1536 + 512 + I0 + t] = sumz;
    } else {
        // ---------------- GEMM1: job j -> (mt=j>>5, nt=j&31)
        unsigned short* Bg = reinterpret_cast<unsigned short*>(smem);   // 32KB
        float* red = reinterpret_cast<float*>(smem + 32768);
        const int j = bid - 256;
        const int mt = j >> 5, nt = j & 31;
        const int w = t >> 6, l = t & 63;
        const int lk = l & 15, kq = l >> 4;
        const int col = nt * 16 + lk;

        #pragma unroll 4
        for (int i = 0; i < 4; ++i) {
            const int ks = w * 4 + i;
            const int kb = ks * 32;
            const float* wb; int krel;
            if (ks < 16) { wb = Wa; krel = kb; } else { wb = Wc; krel = kb - 512; }
            bf16x8 fr;
            #pragma unroll
            for (int jj = 0; jj < 4; ++jj)
                fr[jj] = (__bf16)wb[(size_t)(krel + 4 * kq + jj) * 512 + col];
            #pragma unroll
            for (int jj = 0; jj < 4; ++jj)
                fr[4 + jj] = (__bf16)wb[(size_t)(krel + 16 + 4 * kq + jj) * 512 + col];
            *reinterpret_cast<uint4*>(&Bg[(ks * 64 + l) * 8]) = __builtin_bit_cast(uint4, fr);
        }
        __syncthreads();

        f32x4 acc0 = (f32x4){0.f, 0.f, 0.f, 0.f};
        f32x4 acc1 = (f32x4){0.f, 0.f, 0.f, 0.f};
        #pragma unroll 4
        for (int i = 0; i < 4; ++i) {
            const int ks = w * 4 + i;
            uint4 av = *reinterpret_cast<const uint4*>(apack + ((size_t)(mt * 32 + ks) * 64 + l) * 8);
            uint4 bv = *reinterpret_cast<const uint4*>(&Bg[(ks * 64 + l) * 8]);
            if (i & 1) acc1 = MFMA(av, bv, acc1);
            else       acc0 = MFMA(av, bv, acc0);
        }
        f32x4 sum = acc0 + acc1;

        if (w < 4) {
            #pragma unroll
            for (int r = 0; r < 4; ++r)
                red[w * 272 + (kq * 4 + r) * 17 + lk] = sum[r];
        }
        __syncthreads();
        if (w >= 4) {
            #pragma unroll
            for (int r = 0; r < 4; ++r)
                red[(w - 4) * 272 + (kq * 4 + r) * 17 + lk] += sum[r];
        }
        __syncthreads();
        if (t < 256) {
            const int m = t >> 4, n = t & 15;
            const int o = m * 17 + n;
            const int colo = nt * 16 + n;
            float v = red[o] + red[272 + o] + red[544 + o] + red[816 + o] + ba[colo];
            out[(size_t)(mt * 16 + m) * 1536 + colo] = tanhf(v);
        }
    }
}

extern "C" void kernel_launch(void* const* d_in, const int* in_sizes, int n_in,
                              void* d_out, int out_size, void* d_ws, size_t ws_size,
                              hipStream_t stream) {
    // inputs: 0=t, 1=s, 2=context, 3=Wa, 4=Wc, 5=ba, 6=Wl, 7=bl
    const float* s   = (const float*)d_in[1];
    const float* ctx = (const float*)d_in[2];
    const float* Wa  = (const float*)d_in[3];
    const float* Wc  = (const float*)d_in[4];
    const float* ba  = (const float*)d_in[5];
    const float* Wl  = (const float*)d_in[6];
    const float* bl  = (const float*)d_in[7];
    float* out = (float*)d_out;

    unsigned short* ws16 = (unsigned short*)d_ws;
    float* cws = (float*)((char*)d_ws + C_OFF_BYTES);

    k1<<<272, 512, 0, stream>>>(s, ctx, Wl, bl, ws16, cws);
    k2<<<512, 512, 0, stream>>>(s, Wa, Wc, ba, ws16, cws, out);
}